// Round 1
// baseline (192.725 us; speedup 1.0000x reference)
//
#include <hip/hip_runtime.h>

#define TPB 256
#define EPB 16            // elements per block (16 lanes / element)
#define H1S 246           // padded row stride for h1 (245 used)
#define XSTRIDE 260       // padded row stride for staged x (256 used)

// s_sb (folded BN scale/bias) offsets: per layer [scale[C] | bias[C]]
#define SB_P1 0
#define SB_P2 10
#define SB_R1 30
#define SB_R2 50
#define SB_A1 70
#define SB_B1 210
#define SB_C1 270
#define SB_A2 272
#define SB_B2 412
#define SB_C2 472

__device__ __forceinline__ float block_absmax(const float* __restrict__ p, int n,
                                              float* s_red, int tid) {
  float m = 0.f;
  for (int i = tid; i < n; i += TPB) m = fmaxf(m, fabsf(p[i]));
#pragma unroll
  for (int off = 32; off > 0; off >>= 1)
    m = fmaxf(m, __shfl_down(m, off, 64));
  __syncthreads();                 // protect s_red from previous use
  if ((tid & 63) == 0) s_red[tid >> 6] = m;
  __syncthreads();
  return fmaxf(fmaxf(s_red[0], s_red[1]), fmaxf(s_red[2], s_red[3]));
}

// Quantize exactly like reference: s = amax/127; q = round(clip(w/s,-127,127))*s
// (precise f32 division + rintf == round-half-even, matching jnp.round)
__device__ __forceinline__ void stage_q(float* __restrict__ dst, const float* __restrict__ src,
                                        int n, float amax, int tid) {
  float s = amax / 127.0f;
  for (int i = tid; i < n; i += TPB) {
    float w = src[i];
    float q = rintf(fminf(fmaxf(w / s, -127.f), 127.f)) * s;
    dst[i] = q;
  }
}

#define FOLD(bn, C, OFF)                                                          \
  if (tid < (C)) {                                                                \
    float gg = (bn)[tid], bb = (bn)[(C) + tid];                                   \
    float mm = (bn)[2 * (C) + tid], vv = (bn)[3 * (C) + tid];                     \
    float sc = gg / sqrtf(vv + 1e-5f);                                            \
    s_sb[(OFF) + tid] = sc;                                                       \
    s_sb[(OFF) + (C) + tid] = bb - mm * sc;                                       \
  }

extern "C" __global__ __launch_bounds__(TPB, 2)
void taunet(const float* __restrict__ x,
            const float* __restrict__ w1,  const float* __restrict__ bnp1,
            const float* __restrict__ w2,  const float* __restrict__ bnp2,
            const float* __restrict__ wr1, const float* __restrict__ bnr1,
            const float* __restrict__ wr2, const float* __restrict__ bnr2,
            const float* __restrict__ wa1, const float* __restrict__ bna1,
            const float* __restrict__ wb1, const float* __restrict__ bnb1,
            const float* __restrict__ wc1, const float* __restrict__ bnc1,
            const float* __restrict__ wa2, const float* __restrict__ bna2,
            const float* __restrict__ wb2, const float* __restrict__ bnb2,
            const float* __restrict__ wc2, const float* __restrict__ bnc2,
            float* __restrict__ out, int B)
{
  __shared__ __align__(16) float s_h1[EPB * H1S];   // pre1 out; later the 70-vec
  __shared__ __align__(16) float s_h2[EPB * 140];   // pre2 out; later residual h
  __shared__ __align__(16) float s_t1[EPB * 140];   // r1 out; later the 30-vec
  __shared__ __align__(16) float s_wa[4480];        // x-stage / A-chunk / B weights
  __shared__ __align__(16) float s_w2d[450];
  __shared__ __align__(16) float s_w1d[65];
  __shared__ float s_wr1d[100];
  __shared__ float s_wr2d[100];
  __shared__ float s_wcd[64];
  __shared__ float s_sb[474];
  __shared__ float s_red[4];

  const int tid = threadIdx.x;
  const int g = tid >> 4;     // group = element within block
  const int l = tid & 15;     // lane within group
  const int elem = blockIdx.x * EPB + g;

  // ---- stage x tile into s_wa (coalesced float4), row stride 260 ----
  {
    const float4* xb = (const float4*)x;
    int base = blockIdx.x * (EPB * 64);
    for (int i = tid; i < EPB * 64; i += TPB) {
      int gi = base + i;
      if (gi < B * 64) {
        float4 v = xb[gi];
        int e = i >> 6, c = i & 63;
        *(float4*)&s_wa[e * XSTRIDE + c * 4] = v;
      }
    }
  }

  // ---- fold BN params into (scale, bias) ----
  FOLD(bnp1, 5, SB_P1)  FOLD(bnp2, 10, SB_P2)
  FOLD(bnr1, 10, SB_R1) FOLD(bnr2, 10, SB_R2)
  FOLD(bna1, 70, SB_A1) FOLD(bnb1, 30, SB_B1) FOLD(bnc1, 1, SB_C1)
  FOLD(bna2, 70, SB_A2) FOLD(bnb2, 30, SB_B2) FOLD(bnc2, 1, SB_C2)

  // ---- per-tensor |w| maxima (block reductions; barriers inside) ----
  float axw1 = block_absmax(w1, 65, s_red, tid);
  float axw2 = block_absmax(w2, 450, s_red, tid);
  float axr1 = block_absmax(wr1, 100, s_red, tid);
  float axr2 = block_absmax(wr2, 100, s_red, tid);
  float axa1 = block_absmax(wa1, 9800, s_red, tid);
  float axb1 = block_absmax(wb1, 2100, s_red, tid);
  float axc1 = block_absmax(wc1, 30, s_red, tid);
  float axa2 = block_absmax(wa2, 9800, s_red, tid);
  float axb2 = block_absmax(wb2, 2100, s_red, tid);
  float axc2 = block_absmax(wc2, 30, s_red, tid);

  // ---- stage small quantized weights ----
  stage_q(s_w1d, w1, 65, axw1, tid);
  stage_q(s_w2d, w2, 450, axw2, tid);
  stage_q(s_wr1d, wr1, 100, axr1, tid);
  stage_q(s_wr2d, wr2, 100, axr2, tid);
  stage_q(s_wcd, wc1, 30, axc1, tid);
  stage_q(s_wcd + 32, wc2, 30, axc2, tid);
  __syncthreads();

  // ---- P1: pre1 (Cin=1, K=13, stride 5) -> h1[5][49] ----
  {
    const float* xe = &s_wa[g * XSTRIDE];
#pragma unroll
    for (int rep = 0; rep < 4; ++rep) {
      int p = l + 16 * rep;
      bool act = p < 49;
      int ps = act ? p : 0;
      float win[13];
#pragma unroll
      for (int k = 0; k < 13; ++k) win[k] = xe[5 * ps + k];
#pragma unroll
      for (int ci = 0; ci < 5; ++ci) {
        float a0 = 0.f, a1 = 0.f;
#pragma unroll
        for (int k = 0; k < 13; ++k) {
          float d = fabsf(win[k] - s_w1d[ci * 13 + k]);
          if (k & 1) a1 += d; else a0 += d;
        }
        float v = fmaxf(fmaf(-(a0 + a1), s_sb[SB_P1 + ci], s_sb[SB_P1 + 5 + ci]), 0.f);
        if (act) s_h1[g * H1S + ci * 49 + ps] = v;
      }
    }
  }
  __syncthreads();

  // ---- P2: pre2 (Cin=5, K=9, stride 3) -> h2[10][14]; lane = ow ----
  {
    int ow = (l < 14) ? l : 0;
    float win[45];
#pragma unroll
    for (int ci = 0; ci < 5; ++ci)
#pragma unroll
      for (int k = 0; k < 9; ++k)
        win[ci * 9 + k] = s_h1[g * H1S + ci * 49 + 3 * ow + k];
#pragma unroll
    for (int co = 0; co < 10; ++co) {
      float a0 = 0.f, a1 = 0.f;
#pragma unroll
      for (int j = 0; j < 45; ++j) {
        float d = fabsf(win[j] - s_w2d[co * 45 + j]);
        if (j & 1) a1 += d; else a0 += d;
      }
      float v = fmaxf(fmaf(-(a0 + a1), s_sb[SB_P2 + co], s_sb[SB_P2 + 10 + co]), 0.f);
      if (l < 14) s_h2[g * 140 + co * 14 + ow] = v;
    }
  }
  __syncthreads();

  // ---- P3: r1 (10x10, K=1) + relu -> t1 ----
  {
#pragma unroll
    for (int j = 0; j < 9; ++j) {
      int idx = l + 16 * j;
      if (idx < 140) {
        int co = idx / 14, ow = idx % 14;
        float a0 = 0.f, a1 = 0.f;
#pragma unroll
        for (int ci = 0; ci < 10; ++ci) {
          float d = fabsf(s_h2[g * 140 + ci * 14 + ow] - s_wr1d[co * 10 + ci]);
          if (ci & 1) a1 += d; else a0 += d;
        }
        float v = fmaxf(fmaf(-(a0 + a1), s_sb[SB_R1 + co], s_sb[SB_R1 + 10 + co]), 0.f);
        s_t1[g * 140 + idx] = v;
      }
    }
  }
  __syncthreads();

  // ---- P4: r2 (no relu) + residual, h = relu(t2 + h2), in place ----
  {
#pragma unroll
    for (int j = 0; j < 9; ++j) {
      int idx = l + 16 * j;
      if (idx < 140) {
        int co = idx / 14, ow = idx % 14;
        float a0 = 0.f, a1 = 0.f;
#pragma unroll
        for (int ci = 0; ci < 10; ++ci) {
          float d = fabsf(s_t1[g * 140 + ci * 14 + ow] - s_wr2d[co * 10 + ci]);
          if (ci & 1) a1 += d; else a0 += d;
        }
        float t2 = fmaf(-(a0 + a1), s_sb[SB_R2 + co], s_sb[SB_R2 + 10 + co]);
        s_h2[g * 140 + idx] = fmaxf(t2 + s_h2[g * 140 + idx], 0.f);
      }
    }
  }
  __syncthreads();

  // ---- two output branches ----
  for (int br = 0; br < 2; ++br) {
    const float* wa = br ? wa2 : wa1;
    const float* wb = br ? wb2 : wb1;
    float axa = br ? axa2 : axa1;
    float axb = br ? axb2 : axb1;
    int sbA = br ? SB_A2 : SB_A1;
    int sbB = br ? SB_B2 : SB_B1;
    int sbC = br ? SB_C2 : SB_C1;

    // o?a: 70x140, chunks of 32 output channels through s_wa
    for (int chk = 0; chk < 3; ++chk) {
      int co0 = chk * 32;
      int nco = (chk == 2) ? 6 : 32;
      __syncthreads();                       // prior s_wa readers done
      stage_q(s_wa, wa + co0 * 140, nco * 140, axa, tid);
      __syncthreads();
      int npass = (chk == 2) ? 1 : 2;
      for (int pss = 0; pss < npass; ++pss) {
        int cl = l + 16 * pss;
        bool act = cl < nco;
        int cls = act ? cl : 0;
        const float* hb = &s_h2[g * 140];
        const float* wbp = &s_wa[cls * 140];
        float a0 = 0.f, a1 = 0.f, a2 = 0.f, a3 = 0.f;
#pragma unroll
        for (int cb = 0; cb < 35; ++cb) {
          float4 h4 = *(const float4*)&hb[cb * 4];
          float4 w4 = *(const float4*)&wbp[cb * 4];
          a0 += fabsf(h4.x - w4.x);
          a1 += fabsf(h4.y - w4.y);
          a2 += fabsf(h4.z - w4.z);
          a3 += fabsf(h4.w - w4.w);
        }
        if (act) {
          int co = co0 + cl;
          float sad = (a0 + a1) + (a2 + a3);
          float v = fmaxf(fmaf(-sad, s_sb[sbA + co], s_sb[sbA + 70 + co]), 0.f);
          s_h1[g * H1S + co] = v;
        }
      }
    }
    __syncthreads();
    // o?b weights into s_wa (2100 <= 4480)
    stage_q(s_wa, wb, 2100, axb, tid);
    __syncthreads();
    // o?b: 30x70 -> s_t1[g][0..29]
    {
#pragma unroll
      for (int pss = 0; pss < 2; ++pss) {
        int co = l + 16 * pss;
        bool act = co < 30;
        int cos = act ? co : 0;
        float a0 = 0.f, a1 = 0.f;
#pragma unroll
        for (int ci = 0; ci < 70; ci += 2) {
          a0 += fabsf(s_h1[g * H1S + ci]     - s_wa[cos * 70 + ci]);
          a1 += fabsf(s_h1[g * H1S + ci + 1] - s_wa[cos * 70 + ci + 1]);
        }
        if (act) {
          float v = fmaxf(fmaf(-(a0 + a1), s_sb[sbB + cos], s_sb[sbB + 30 + cos]), 0.f);
          s_t1[g * 140 + cos] = v;
        }
      }
    }
    __syncthreads();
    // o?c: 1x30 -> out
    if (l == 0 && elem < B) {
      float a0 = 0.f, a1 = 0.f;
#pragma unroll
      for (int ci = 0; ci < 30; ci += 2) {
        a0 += fabsf(s_t1[g * 140 + ci]     - s_wcd[br * 32 + ci]);
        a1 += fabsf(s_t1[g * 140 + ci + 1] - s_wcd[br * 32 + ci + 1]);
      }
      float v = fmaxf(fmaf(-(a0 + a1), s_sb[sbC], s_sb[sbC + 1]), 0.f);
      out[br * B + elem] = v;
    }
    __syncthreads();   // protect s_t1 / s_wa before next branch
  }
}

extern "C" void kernel_launch(void* const* d_in, const int* in_sizes, int n_in,
                              void* d_out, int out_size, void* d_ws, size_t ws_size,
                              hipStream_t stream) {
  const float* x    = (const float*)d_in[0];
  const float* w1   = (const float*)d_in[1];
  const float* bnp1 = (const float*)d_in[2];
  const float* w2   = (const float*)d_in[3];
  const float* bnp2 = (const float*)d_in[4];
  const float* wr1  = (const float*)d_in[5];
  const float* bnr1 = (const float*)d_in[6];
  const float* wr2  = (const float*)d_in[7];
  const float* bnr2 = (const float*)d_in[8];
  const float* wa1  = (const float*)d_in[9];
  const float* bna1 = (const float*)d_in[10];
  const float* wb1  = (const float*)d_in[11];
  const float* bnb1 = (const float*)d_in[12];
  const float* wc1  = (const float*)d_in[13];
  const float* bnc1 = (const float*)d_in[14];
  const float* wa2  = (const float*)d_in[15];
  const float* bna2 = (const float*)d_in[16];
  const float* wb2  = (const float*)d_in[17];
  const float* bnb2 = (const float*)d_in[18];
  const float* wc2  = (const float*)d_in[19];
  const float* bnc2 = (const float*)d_in[20];

  int B = in_sizes[0] / 256;
  int blocks = (B + EPB - 1) / EPB;

  hipLaunchKernelGGL(taunet, dim3(blocks), dim3(TPB), 0, stream,
                     x, w1, bnp1, w2, bnp2, wr1, bnr1, wr2, bnr2,
                     wa1, bna1, wb1, bnb1, wc1, bnc1,
                     wa2, bna2, wb2, bnb2, wc2, bnc2,
                     (float*)d_out, B);
}